// Round 2
// baseline (4952.317 us; speedup 1.0000x reference)
//
#include <hip/hip_runtime.h>
#include <math.h>

// Problem constants
#define B_ 2
#define L_ 2048
#define D_ 3072
#define H_ 24
#define KV_ 8
#define HD_ 128
#define GROUP_ 3
#define SCALE_ 0.08838834764831845f  // 128^-0.5
// ln(500000) / 64
#define NEG_LOG_THETA_OVER_HALF 0.20503692627f

// ---------------------------------------------------------------------------
// Tiled fp32 GEMM: C[M,N] = A[M,K] @ B[K,N], all row-major.
// 128x128 tile, BK=16, 256 threads, 8x8 micro-tile per thread.
// M % 128 == 0, N % 128 == 0, K % 16 == 0 (true for all our shapes).
// ---------------------------------------------------------------------------
__global__ __launch_bounds__(256, 2) void gemm_f32(const float* __restrict__ A,
                                                   const float* __restrict__ Bm,
                                                   float* __restrict__ C,
                                                   int M, int N, int K) {
    __shared__ float As[16][132];  // stored transposed: As[k][m]
    __shared__ float Bs[16][132];  // Bs[k][n]

    const int tid = threadIdx.x;
    const int m0 = blockIdx.y * 128;
    const int n0 = blockIdx.x * 128;
    const int tx = tid & 15;   // 0..15  -> cols tx*8..tx*8+7
    const int ty = tid >> 4;   // 0..15  -> rows ty*8..ty*8+7

    // global->LDS load mapping
    const int a_m = tid >> 2;          // 0..63 (also +64)
    const int a_k = (tid & 3) << 2;    // 0,4,8,12
    const int b_n = (tid & 31) << 2;   // 0..124
    const int b_k = tid >> 5;          // 0..7 (also +8)

    float acc[8][8];
#pragma unroll
    for (int i = 0; i < 8; ++i)
#pragma unroll
        for (int j = 0; j < 8; ++j) acc[i][j] = 0.0f;

    const float* Aptr  = A + (size_t)(m0 + a_m) * K + a_k;
    const float* Aptr2 = Aptr + (size_t)64 * K;
    const float* Bptr  = Bm + (size_t)b_k * N + n0 + b_n;
    const float* Bptr2 = Bptr + (size_t)8 * N;

    for (int kt = 0; kt < K; kt += 16) {
        const float4 a0 = *(const float4*)(Aptr + kt);
        const float4 a1 = *(const float4*)(Aptr2 + kt);
        const float4 b0 = *(const float4*)(Bptr + (size_t)kt * N);
        const float4 b1 = *(const float4*)(Bptr2 + (size_t)kt * N);

        __syncthreads();  // previous iteration's reads must finish
        As[a_k + 0][a_m] = a0.x; As[a_k + 1][a_m] = a0.y;
        As[a_k + 2][a_m] = a0.z; As[a_k + 3][a_m] = a0.w;
        As[a_k + 0][a_m + 64] = a1.x; As[a_k + 1][a_m + 64] = a1.y;
        As[a_k + 2][a_m + 64] = a1.z; As[a_k + 3][a_m + 64] = a1.w;
        *(float4*)&Bs[b_k][b_n]     = b0;
        *(float4*)&Bs[b_k + 8][b_n] = b1;
        __syncthreads();

#pragma unroll
        for (int kk = 0; kk < 16; ++kk) {
            const float4 x0 = *(const float4*)&As[kk][ty * 8];
            const float4 x1 = *(const float4*)&As[kk][ty * 8 + 4];
            const float4 y0 = *(const float4*)&Bs[kk][tx * 8];
            const float4 y1 = *(const float4*)&Bs[kk][tx * 8 + 4];
            const float av[8] = {x0.x, x0.y, x0.z, x0.w, x1.x, x1.y, x1.z, x1.w};
            const float bv[8] = {y0.x, y0.y, y0.z, y0.w, y1.x, y1.y, y1.z, y1.w};
#pragma unroll
            for (int i = 0; i < 8; ++i)
#pragma unroll
                for (int j = 0; j < 8; ++j)
                    acc[i][j] = fmaf(av[i], bv[j], acc[i][j]);
        }
    }

#pragma unroll
    for (int i = 0; i < 8; ++i) {
        float* crow = C + (size_t)(m0 + ty * 8 + i) * N + n0 + tx * 8;
        *(float4*)crow       = make_float4(acc[i][0], acc[i][1], acc[i][2], acc[i][3]);
        *(float4*)(crow + 4) = make_float4(acc[i][4], acc[i][5], acc[i][6], acc[i][7]);
    }
}

// ---------------------------------------------------------------------------
// RoPE (half-split / llama style), applied in place to q [B,L,H,HD] and
// k [B,L,KV,HD]. One thread per (b,l,head,i<64) pair.
// ---------------------------------------------------------------------------
__global__ void rope_f32(float* __restrict__ q, float* __restrict__ k) {
    const size_t nq = (size_t)B_ * L_ * H_ * 64;   // 6291456
    const size_t nk = (size_t)B_ * L_ * KV_ * 64;  // 2097152
    size_t idx = (size_t)blockIdx.x * blockDim.x + threadIdx.x;
    float* base;
    int heads;
    if (idx < nq) {
        base = q; heads = H_;
    } else if (idx < nq + nk) {
        base = k; heads = KV_; idx -= nq;
    } else {
        return;
    }
    const int i = (int)(idx & 63);
    const size_t rem = idx >> 6;          // (b*L + l)*heads + h
    const int l = (int)((rem / heads) % L_);

    const float inv_freq = expf(-(float)i * NEG_LOG_THETA_OVER_HALF);
    const float ang = (float)l * inv_freq;
    float s, c;
    sincosf(ang, &s, &c);

    const size_t off = rem * HD_ + i;
    const float x1 = base[off];
    const float x2 = base[off + 64];
    base[off]      = x1 * c - x2 * s;
    base[off + 64] = x2 * c + x1 * s;
}

// ---------------------------------------------------------------------------
// Causal GQA flash attention, fp32.
// Grid: (L/64, B*H). Block: 256 threads.
// Per block: 64 query rows, K/V tiles of 32 rows staged through LDS.
// Thread (rg=tid/16, cg=tid%16): scores micro-tile = 4 q-rows x 2 k-cols;
// output micro-tile = 4 q-rows x 8 dims (dims cg*8..cg*8+7).
// Row reductions via shfl across the 16-lane group.
// ---------------------------------------------------------------------------
__global__ __launch_bounds__(256) void attn_f32(const float* __restrict__ qg,
                                                const float* __restrict__ kg,
                                                const float* __restrict__ vg,
                                                float* __restrict__ att) {
    __shared__ float q_s[64][132];
    __shared__ float kv_s[32][132];

    const int tid = threadIdx.x;
    const int qt = blockIdx.x;
    const int bh = blockIdx.y;
    const int b = bh / H_;
    const int h = bh % H_;
    const int g = h / GROUP_;  // kv head

    // ---- stage Q tile ----
    {
        const int r = tid >> 2;
        const int c0 = (tid & 3) << 5;
        const float* src =
            qg + ((size_t)(b * L_ + qt * 64 + r) * H_ + h) * HD_ + c0;
#pragma unroll
        for (int i = 0; i < 8; ++i)
            *(float4*)&q_s[r][c0 + 4 * i] = *(const float4*)(src + 4 * i);
    }

    const int rg = tid >> 4;  // 0..15 -> rows rg*4..rg*4+3
    const int cg = tid & 15;  // 0..15 -> k-cols cg*2, cg*2+1; dims cg*8..+7

    float m_i[4], l_i[4], o_acc[4][8];
#pragma unroll
    for (int r = 0; r < 4; ++r) {
        m_i[r] = -INFINITY;
        l_i[r] = 0.0f;
#pragma unroll
        for (int d = 0; d < 8; ++d) o_acc[r][d] = 0.0f;
    }

    const int lr = tid >> 3;          // 0..31 (K/V stage row)
    const int lc = (tid & 7) << 2;    // 0..28 (K/V stage col base)
    const int nkt = 2 * (qt + 1);     // causal: k rows 0 .. (qt+1)*64-1

    for (int kt = 0; kt < nkt; ++kt) {
        // ---- stage K tile ----
        float4 kreg[4];
        {
            const float* src =
                kg + ((size_t)(b * L_ + kt * 32 + lr) * KV_ + g) * HD_ + lc;
#pragma unroll
            for (int i = 0; i < 4; ++i) kreg[i] = *(const float4*)(src + 32 * i);
        }
        __syncthreads();  // previous PV reads done
#pragma unroll
        for (int i = 0; i < 4; ++i) *(float4*)&kv_s[lr][lc + 32 * i] = kreg[i];
        __syncthreads();

        // ---- scores: 4 rows x 2 cols ----
        float sc0[4] = {0.f, 0.f, 0.f, 0.f};
        float sc1[4] = {0.f, 0.f, 0.f, 0.f};
#pragma unroll 8
        for (int d = 0; d < 128; d += 4) {
            const float4 k0 = *(const float4*)&kv_s[cg * 2][d];
            const float4 k1 = *(const float4*)&kv_s[cg * 2 + 1][d];
#pragma unroll
            for (int r = 0; r < 4; ++r) {
                const float4 qv = *(const float4*)&q_s[rg * 4 + r][d];
                sc0[r] += qv.x * k0.x + qv.y * k0.y + qv.z * k0.z + qv.w * k0.w;
                sc1[r] += qv.x * k1.x + qv.y * k1.y + qv.z * k1.z + qv.w * k1.w;
            }
        }

        // ---- mask + scale + online softmax update ----
        float p0[4], p1[4];
#pragma unroll
        for (int r = 0; r < 4; ++r) {
            const int qi = qt * 64 + rg * 4 + r;
            const int kj0 = kt * 32 + cg * 2;
            const float s0 = (kj0 <= qi) ? sc0[r] * SCALE_ : -INFINITY;
            const float s1 = (kj0 + 1 <= qi) ? sc1[r] * SCALE_ : -INFINITY;
            float tm = fmaxf(s0, s1);
#pragma unroll
            for (int off = 1; off < 16; off <<= 1)
                tm = fmaxf(tm, __shfl_xor(tm, off, 16));
            const float mn = fmaxf(m_i[r], tm);
            const float fac = __expf(m_i[r] - mn);  // exp(-inf)=0 at kt==0
            m_i[r] = mn;
            p0[r] = __expf(s0 - mn);
            p1[r] = __expf(s1 - mn);
            float ls = p0[r] + p1[r];
#pragma unroll
            for (int off = 1; off < 16; off <<= 1)
                ls += __shfl_xor(ls, off, 16);
            l_i[r] = l_i[r] * fac + ls;
#pragma unroll
            for (int d = 0; d < 8; ++d) o_acc[r][d] *= fac;
        }

        // ---- stage V tile (reuse kv_s) ----
        float4 vreg[4];
        {
            const float* src =
                vg + ((size_t)(b * L_ + kt * 32 + lr) * KV_ + g) * HD_ + lc;
#pragma unroll
            for (int i = 0; i < 4; ++i) vreg[i] = *(const float4*)(src + 32 * i);
        }
        __syncthreads();  // score reads of K done
#pragma unroll
        for (int i = 0; i < 4; ++i) *(float4*)&kv_s[lr][lc + 32 * i] = vreg[i];
        __syncthreads();

        // ---- PV accumulation ----
#pragma unroll 8
        for (int j = 0; j < 32; ++j) {
            const float4 v0 = *(const float4*)&kv_s[j][cg * 8];
            const float4 v1 = *(const float4*)&kv_s[j][cg * 8 + 4];
            float pj[4];
#pragma unroll
            for (int r = 0; r < 4; ++r) {
                const float pv = (j & 1) ? p1[r] : p0[r];
                pj[r] = __shfl(pv, j >> 1, 16);
            }
#pragma unroll
            for (int r = 0; r < 4; ++r) {
                o_acc[r][0] = fmaf(pj[r], v0.x, o_acc[r][0]);
                o_acc[r][1] = fmaf(pj[r], v0.y, o_acc[r][1]);
                o_acc[r][2] = fmaf(pj[r], v0.z, o_acc[r][2]);
                o_acc[r][3] = fmaf(pj[r], v0.w, o_acc[r][3]);
                o_acc[r][4] = fmaf(pj[r], v1.x, o_acc[r][4]);
                o_acc[r][5] = fmaf(pj[r], v1.y, o_acc[r][5]);
                o_acc[r][6] = fmaf(pj[r], v1.z, o_acc[r][6]);
                o_acc[r][7] = fmaf(pj[r], v1.w, o_acc[r][7]);
            }
        }
    }

    // ---- epilogue: divide by l and store to att [B,L,H,HD] ----
#pragma unroll
    for (int r = 0; r < 4; ++r) {
        const float inv = 1.0f / l_i[r];
        const int qi = qt * 64 + rg * 4 + r;
        float* dst = att + ((size_t)(b * L_ + qi) * H_ + h) * HD_ + cg * 8;
        *(float4*)dst = make_float4(o_acc[r][0] * inv, o_acc[r][1] * inv,
                                    o_acc[r][2] * inv, o_acc[r][3] * inv);
        *(float4*)(dst + 4) = make_float4(o_acc[r][4] * inv, o_acc[r][5] * inv,
                                          o_acc[r][6] * inv, o_acc[r][7] * inv);
    }
}

// ---------------------------------------------------------------------------
extern "C" void kernel_launch(void* const* d_in, const int* in_sizes, int n_in,
                              void* d_out, int out_size, void* d_ws, size_t ws_size,
                              hipStream_t stream) {
    const float* x  = (const float*)d_in[0];   // [B,L,D]
    const float* Wq = (const float*)d_in[1];   // [D, H*HD]
    const float* Wk = (const float*)d_in[2];   // [D, KV*HD]
    const float* Wv = (const float*)d_in[3];   // [D, KV*HD]
    const float* Wo = (const float*)d_in[4];   // [H*HD, D]
    float* out = (float*)d_out;                // [B,L,D]

    // Workspace layout (floats): q | k | v | att  = 128 MiB total
    float* q   = (float*)d_ws;
    float* k   = q + (size_t)B_ * L_ * H_ * HD_;    // +12582912
    float* v   = k + (size_t)B_ * L_ * KV_ * HD_;   // +4194304
    float* att = v + (size_t)B_ * L_ * KV_ * HD_;   // +4194304

    const int M = B_ * L_;  // 4096
    dim3 blk(256);

    // QKV projections
    gemm_f32<<<dim3((H_ * HD_) / 128, M / 128), blk, 0, stream>>>(
        x, Wq, q, M, H_ * HD_, D_);
    gemm_f32<<<dim3((KV_ * HD_) / 128, M / 128), blk, 0, stream>>>(
        x, Wk, k, M, KV_ * HD_, D_);
    gemm_f32<<<dim3((KV_ * HD_) / 128, M / 128), blk, 0, stream>>>(
        x, Wv, v, M, KV_ * HD_, D_);

    // RoPE on q and k (in place)
    const size_t nrope = (size_t)B_ * L_ * (H_ + KV_) * 64;  // 8388608
    rope_f32<<<dim3((unsigned)(nrope / 256)), blk, 0, stream>>>(q, k);

    // Causal GQA flash attention
    attn_f32<<<dim3(L_ / 64, B_ * H_), blk, 0, stream>>>(q, k, v, att);

    // Output projection
    gemm_f32<<<dim3(D_ / 128, M / 128), blk, 0, stream>>>(
        att, Wo, out, M, D_, H_ * HD_);
}

// Round 3
// 2445.803 us; speedup vs baseline: 2.0248x; 2.0248x over previous
//
#include <hip/hip_runtime.h>
#include <math.h>

// Problem constants
#define B_ 2
#define L_ 2048
#define D_ 3072
#define H_ 24
#define KV_ 8
#define HD_ 128
#define GROUP_ 3
#define SCALE_ 0.08838834764831845f  // 128^-0.5
#define NEG_LOG_THETA_OVER_HALF 0.20503692627f  // ln(500000)/64

typedef __attribute__((ext_vector_type(4))) float f32x4;
typedef __attribute__((ext_vector_type(8))) short s16x8;
typedef __attribute__((ext_vector_type(8))) unsigned short u16x8;
typedef __attribute__((ext_vector_type(4))) unsigned short u16x4;

__device__ inline float b2f(unsigned short u) {
    union { unsigned int i; float f; } x;
    x.i = ((unsigned int)u) << 16;
    return x.f;
}
__device__ inline unsigned short f2b(float f) {
    union { float f; unsigned int i; } x;
    x.f = f;
    unsigned int r = x.i + 0x7FFFu + ((x.i >> 16) & 1u);  // RNE
    return (unsigned short)(r >> 16);
}

__device__ inline void gl16(const unsigned short* g, unsigned short* l) {
    // global -> LDS direct DMA, 16B/lane; LDS dest = wave-uniform base + lane*16
    __builtin_amdgcn_global_load_lds(
        (const __attribute__((address_space(1))) void*)g,
        (__attribute__((address_space(3))) void*)l, 16, 0, 0);
}

// ---------------------------------------------------------------------------
// fp32 -> bf16 row-major convert
// ---------------------------------------------------------------------------
__global__ void conv_f32_bf16(const float* __restrict__ in,
                              unsigned short* __restrict__ out, int n) {
    int i = (blockIdx.x * blockDim.x + threadIdx.x) * 4;
    if (i < n) {
        float4 v = *(const float4*)(in + i);
        u16x4 o;
        o.x = f2b(v.x); o.y = f2b(v.y); o.z = f2b(v.z); o.w = f2b(v.w);
        *(u16x4*)(out + i) = o;
    }
}

// ---------------------------------------------------------------------------
// W [K][N] fp32 -> Wt [N][K] bf16 (tiled transpose+convert). K,N % 32 == 0.
// ---------------------------------------------------------------------------
__global__ void transp_f32_bf16(const float* __restrict__ in,
                                unsigned short* __restrict__ out, int K, int N) {
    __shared__ unsigned short t[32][33];
    const int n0 = blockIdx.x * 32, k0 = blockIdx.y * 32;
    const int tx = threadIdx.x & 31, ty = threadIdx.x >> 5;  // 32 x 8
#pragma unroll
    for (int i = 0; i < 4; ++i)
        t[tx][ty + 8 * i] = f2b(in[(size_t)(k0 + ty + 8 * i) * N + n0 + tx]);
    __syncthreads();
#pragma unroll
    for (int i = 0; i < 4; ++i)
        out[(size_t)(n0 + ty + 8 * i) * K + k0 + tx] = t[ty + 8 * i][tx];
}

// ---------------------------------------------------------------------------
// bf16 MFMA GEMM (m97 structure): C[M,N] = A[M,K] @ Bt[N,K]^T
// A row-major bf16, Bt row-major bf16 (i.e. B transposed). 128x128 tile,
// BK=32, 256 threads = 4 waves (2x2), each wave 64x64 = 4x4 16x16 frags.
// Double-buffered LDS staged via global_load_lds dwordx4.
// ---------------------------------------------------------------------------
template <int OUTBF>
__global__ void gemm_bf16(const unsigned short* __restrict__ A,
                          const unsigned short* __restrict__ Bt,
                          void* __restrict__ Cv, int M, int N, int K) {
    // [buf][ A: 0..4096 | B: 4096..8192 ] ushorts; A tile 128x32, row stride 32
    __shared__ unsigned short sm[2][8192];

    const int tid = threadIdx.x;
    const int w = tid >> 6, lane = tid & 63;
    const int m0 = blockIdx.y * 128, n0 = blockIdx.x * 128;
    const int wm = w >> 1, wn = w & 1;
    const int l15 = lane & 15, l4 = lane >> 4;

    // staging: 512 16B-blocks per tile; wave w call c covers blocks (w+4c)*64+lane
    const int bi0 = w * 64 + lane, bi1 = (w + 4) * 64 + lane;
    const unsigned short* gA0 = A + (size_t)(m0 + (bi0 >> 2)) * K + (bi0 & 3) * 8;
    const unsigned short* gA1 = A + (size_t)(m0 + (bi1 >> 2)) * K + (bi1 & 3) * 8;
    const unsigned short* gB0 = Bt + (size_t)(n0 + (bi0 >> 2)) * K + (bi0 & 3) * 8;
    const unsigned short* gB1 = Bt + (size_t)(n0 + (bi1 >> 2)) * K + (bi1 & 3) * 8;
    const int lA0 = w * 512, lA1 = (w + 4) * 512;
    const int lB0 = 4096 + w * 512, lB1 = 4096 + (w + 4) * 512;

    f32x4 acc[4][4];
#pragma unroll
    for (int i = 0; i < 4; ++i)
#pragma unroll
        for (int j = 0; j < 4; ++j) acc[i][j] = (f32x4){0.f, 0.f, 0.f, 0.f};

    int aoff[4], boff[4];
#pragma unroll
    for (int i = 0; i < 4; ++i) {
        aoff[i] = (wm * 64 + i * 16 + l15) * 32 + l4 * 8;
        boff[i] = 4096 + (wn * 64 + i * 16 + l15) * 32 + l4 * 8;
    }

    const int nsteps = K >> 5;

    // prologue: stage tile 0
    gl16(gA0, &sm[0][lA0]);
    gl16(gA1, &sm[0][lA1]);
    gl16(gB0, &sm[0][lB0]);
    gl16(gB1, &sm[0][lB1]);
    __syncthreads();

    int buf = 0;
    for (int s = 0; s < nsteps; ++s) {
        if (s + 1 < nsteps) {
            const int kt = (s + 1) << 5;
            gl16(gA0 + kt, &sm[buf ^ 1][lA0]);
            gl16(gA1 + kt, &sm[buf ^ 1][lA1]);
            gl16(gB0 + kt, &sm[buf ^ 1][lB0]);
            gl16(gB1 + kt, &sm[buf ^ 1][lB1]);
        }
        s16x8 af[4], bfr[4];
#pragma unroll
        for (int i = 0; i < 4; ++i) af[i] = *(const s16x8*)&sm[buf][aoff[i]];
#pragma unroll
        for (int i = 0; i < 4; ++i) bfr[i] = *(const s16x8*)&sm[buf][boff[i]];
#pragma unroll
        for (int mi = 0; mi < 4; ++mi)
#pragma unroll
            for (int ni = 0; ni < 4; ++ni)
                acc[mi][ni] = __builtin_amdgcn_mfma_f32_16x16x32_bf16(
                    af[mi], bfr[ni], acc[mi][ni], 0, 0, 0);
        __syncthreads();
        buf ^= 1;
    }

    // epilogue: D[row][col]: col = lane&15, row = (lane>>4)*4 + r  (m89-verified)
#pragma unroll
    for (int mi = 0; mi < 4; ++mi)
#pragma unroll
        for (int ni = 0; ni < 4; ++ni) {
            const int row0 = m0 + wm * 64 + mi * 16 + l4 * 4;
            const int col = n0 + wn * 64 + ni * 16 + l15;
#pragma unroll
            for (int r = 0; r < 4; ++r) {
                if (OUTBF)
                    ((unsigned short*)Cv)[(size_t)(row0 + r) * N + col] =
                        f2b(acc[mi][ni][r]);
                else
                    ((float*)Cv)[(size_t)(row0 + r) * N + col] = acc[mi][ni][r];
            }
        }
}

// ---------------------------------------------------------------------------
// RoPE in place on bf16 q [B,L,H,HD] and k [B,L,KV,HD].
// ---------------------------------------------------------------------------
__global__ void rope_bf16(unsigned short* __restrict__ q,
                          unsigned short* __restrict__ k) {
    const size_t nq = (size_t)B_ * L_ * H_ * 64;
    const size_t nk = (size_t)B_ * L_ * KV_ * 64;
    size_t idx = (size_t)blockIdx.x * blockDim.x + threadIdx.x;
    unsigned short* base;
    int heads;
    if (idx < nq) {
        base = q; heads = H_;
    } else if (idx < nq + nk) {
        base = k; heads = KV_; idx -= nq;
    } else {
        return;
    }
    const int i = (int)(idx & 63);
    const size_t rem = idx >> 6;
    const int l = (int)((rem / heads) % L_);

    const float inv_freq = expf(-(float)i * NEG_LOG_THETA_OVER_HALF);
    const float ang = (float)l * inv_freq;
    float s, c;
    sincosf(ang, &s, &c);

    const size_t off = rem * HD_ + i;
    const float x1 = b2f(base[off]);
    const float x2 = b2f(base[off + 64]);
    base[off] = f2b(x1 * c - x2 * s);
    base[off + 64] = f2b(x2 * c + x1 * s);
}

// ---------------------------------------------------------------------------
// Causal GQA flash attention, fp32 compute, bf16 in/out.
// Grid: (L/64, B*H). Block: 256.
// ---------------------------------------------------------------------------
__global__ __launch_bounds__(256) void attn_bf16(
    const unsigned short* __restrict__ qg, const unsigned short* __restrict__ kg,
    const unsigned short* __restrict__ vg, unsigned short* __restrict__ att) {
    __shared__ float q_s[64][132];
    __shared__ float kv_s[32][132];

    const int tid = threadIdx.x;
    const int qt = blockIdx.x;
    const int bh = blockIdx.y;
    const int b = bh / H_;
    const int h = bh % H_;
    const int g = h / GROUP_;

    // ---- stage Q tile ----
    {
        const int r = tid >> 2;
        const int c0 = (tid & 3) << 5;
        const unsigned short* src =
            qg + ((size_t)(b * L_ + qt * 64 + r) * H_ + h) * HD_ + c0;
#pragma unroll
        for (int i = 0; i < 4; ++i) {
            u16x8 u = *(const u16x8*)(src + 8 * i);
#pragma unroll
            for (int j = 0; j < 8; ++j) q_s[r][c0 + 8 * i + j] = b2f(u[j]);
        }
    }

    const int rg = tid >> 4;
    const int cg = tid & 15;

    float m_i[4], l_i[4], o_acc[4][8];
#pragma unroll
    for (int r = 0; r < 4; ++r) {
        m_i[r] = -INFINITY;
        l_i[r] = 0.0f;
#pragma unroll
        for (int d = 0; d < 8; ++d) o_acc[r][d] = 0.0f;
    }

    const int lr = tid >> 3;
    const int lc = (tid & 7) << 2;
    const int nkt = 2 * (qt + 1);

    for (int kt = 0; kt < nkt; ++kt) {
        // ---- stage K tile ----
        u16x4 kreg[4];
        {
            const unsigned short* src =
                kg + ((size_t)(b * L_ + kt * 32 + lr) * KV_ + g) * HD_ + lc;
#pragma unroll
            for (int i = 0; i < 4; ++i) kreg[i] = *(const u16x4*)(src + 32 * i);
        }
        __syncthreads();
#pragma unroll
        for (int i = 0; i < 4; ++i)
#pragma unroll
            for (int j = 0; j < 4; ++j) kv_s[lr][lc + 32 * i + j] = b2f(kreg[i][j]);
        __syncthreads();

        // ---- scores ----
        float sc0[4] = {0.f, 0.f, 0.f, 0.f};
        float sc1[4] = {0.f, 0.f, 0.f, 0.f};
#pragma unroll 8
        for (int d = 0; d < 128; d += 4) {
            const float4 k0 = *(const float4*)&kv_s[cg * 2][d];
            const float4 k1 = *(const float4*)&kv_s[cg * 2 + 1][d];
#pragma unroll
            for (int r = 0; r < 4; ++r) {
                const float4 qv = *(const float4*)&q_s[rg * 4 + r][d];
                sc0[r] += qv.x * k0.x + qv.y * k0.y + qv.z * k0.z + qv.w * k0.w;
                sc1[r] += qv.x * k1.x + qv.y * k1.y + qv.z * k1.z + qv.w * k1.w;
            }
        }

        // ---- mask + online softmax ----
        float p0[4], p1[4];
#pragma unroll
        for (int r = 0; r < 4; ++r) {
            const int qi = qt * 64 + rg * 4 + r;
            const int kj0 = kt * 32 + cg * 2;
            const float s0 = (kj0 <= qi) ? sc0[r] * SCALE_ : -INFINITY;
            const float s1 = (kj0 + 1 <= qi) ? sc1[r] * SCALE_ : -INFINITY;
            float tm = fmaxf(s0, s1);
#pragma unroll
            for (int off = 1; off < 16; off <<= 1)
                tm = fmaxf(tm, __shfl_xor(tm, off, 16));
            const float mn = fmaxf(m_i[r], tm);
            const float fac = __expf(m_i[r] - mn);
            m_i[r] = mn;
            p0[r] = __expf(s0 - mn);
            p1[r] = __expf(s1 - mn);
            float ls = p0[r] + p1[r];
#pragma unroll
            for (int off = 1; off < 16; off <<= 1)
                ls += __shfl_xor(ls, off, 16);
            l_i[r] = l_i[r] * fac + ls;
#pragma unroll
            for (int d = 0; d < 8; ++d) o_acc[r][d] *= fac;
        }

        // ---- stage V tile ----
        u16x4 vreg[4];
        {
            const unsigned short* src =
                vg + ((size_t)(b * L_ + kt * 32 + lr) * KV_ + g) * HD_ + lc;
#pragma unroll
            for (int i = 0; i < 4; ++i) vreg[i] = *(const u16x4*)(src + 32 * i);
        }
        __syncthreads();
#pragma unroll
        for (int i = 0; i < 4; ++i)
#pragma unroll
            for (int j = 0; j < 4; ++j) kv_s[lr][lc + 32 * i + j] = b2f(vreg[i][j]);
        __syncthreads();

        // ---- PV ----
#pragma unroll 8
        for (int j = 0; j < 32; ++j) {
            const float4 v0 = *(const float4*)&kv_s[j][cg * 8];
            const float4 v1 = *(const float4*)&kv_s[j][cg * 8 + 4];
            float pj[4];
#pragma unroll
            for (int r = 0; r < 4; ++r) {
                const float pv = (j & 1) ? p1[r] : p0[r];
                pj[r] = __shfl(pv, j >> 1, 16);
            }
#pragma unroll
            for (int r = 0; r < 4; ++r) {
                o_acc[r][0] = fmaf(pj[r], v0.x, o_acc[r][0]);
                o_acc[r][1] = fmaf(pj[r], v0.y, o_acc[r][1]);
                o_acc[r][2] = fmaf(pj[r], v0.z, o_acc[r][2]);
                o_acc[r][3] = fmaf(pj[r], v0.w, o_acc[r][3]);
                o_acc[r][4] = fmaf(pj[r], v1.x, o_acc[r][4]);
                o_acc[r][5] = fmaf(pj[r], v1.y, o_acc[r][5]);
                o_acc[r][6] = fmaf(pj[r], v1.z, o_acc[r][6]);
                o_acc[r][7] = fmaf(pj[r], v1.w, o_acc[r][7]);
            }
        }
    }

    // ---- epilogue: bf16 store ----
#pragma unroll
    for (int r = 0; r < 4; ++r) {
        const float inv = 1.0f / l_i[r];
        const int qi = qt * 64 + rg * 4 + r;
        unsigned short* dst =
            att + ((size_t)(b * L_ + qi) * H_ + h) * HD_ + cg * 8;
        u16x8 o;
#pragma unroll
        for (int j = 0; j < 8; ++j) o[j] = f2b(o_acc[r][j] * inv);
        *(u16x8*)dst = o;
    }
}

// ---------------------------------------------------------------------------
extern "C" void kernel_launch(void* const* d_in, const int* in_sizes, int n_in,
                              void* d_out, int out_size, void* d_ws, size_t ws_size,
                              hipStream_t stream) {
    const float* x = (const float*)d_in[0];    // [B,L,D]
    const float* Wq = (const float*)d_in[1];   // [D, H*HD]
    const float* Wk = (const float*)d_in[2];   // [D, KV*HD]
    const float* Wv = (const float*)d_in[3];   // [D, KV*HD]
    const float* Wo = (const float*)d_in[4];   // [H*HD, D]
    float* out = (float*)d_out;                // [B,L,D]

    // Workspace carve (bytes), total 117,440,512 <= 128 MiB proven budget.
    char* ws = (char*)d_ws;
    unsigned short* xb  = (unsigned short*)(ws);              // 25,165,824 B
    unsigned short* qb  = (unsigned short*)(ws + 25165824);   // 25,165,824 B
    unsigned short* kb  = (unsigned short*)(ws + 50331648);   //  8,388,608 B
    unsigned short* vb  = (unsigned short*)(ws + 58720256);   //  8,388,608 B
    unsigned short* Wot = (unsigned short*)(ws + 67108864);   // 18,874,368 B
    unsigned short* Wqt = (unsigned short*)(ws + 85983232);   // 18,874,368 B
    unsigned short* Wkt = (unsigned short*)(ws + 104857600);  //  6,291,456 B
    unsigned short* Wvt = (unsigned short*)(ws + 111149056);  //  6,291,456 B
    unsigned short* attb = (unsigned short*)(ws + 85983232);  // alias Wqt/Wkt (dead by then)

    const int M = B_ * L_;  // 4096
    dim3 blk(256);

    // prep: convert x, transpose+convert weights
    conv_f32_bf16<<<dim3(12288), blk, 0, stream>>>(x, xb, M * D_);
    transp_f32_bf16<<<dim3(96, 96), blk, 0, stream>>>(Wq, Wqt, D_, H_ * HD_);
    transp_f32_bf16<<<dim3(32, 96), blk, 0, stream>>>(Wk, Wkt, D_, KV_ * HD_);
    transp_f32_bf16<<<dim3(32, 96), blk, 0, stream>>>(Wv, Wvt, D_, KV_ * HD_);
    transp_f32_bf16<<<dim3(96, 96), blk, 0, stream>>>(Wo, Wot, H_ * HD_, D_);

    // QKV projections (bf16 MFMA, bf16 out)
    gemm_bf16<1><<<dim3((H_ * HD_) / 128, M / 128), blk, 0, stream>>>(
        xb, Wqt, qb, M, H_ * HD_, D_);
    gemm_bf16<1><<<dim3((KV_ * HD_) / 128, M / 128), blk, 0, stream>>>(
        xb, Wkt, kb, M, KV_ * HD_, D_);
    gemm_bf16<1><<<dim3((KV_ * HD_) / 128, M / 128), blk, 0, stream>>>(
        xb, Wvt, vb, M, KV_ * HD_, D_);

    // RoPE in place (bf16)
    rope_bf16<<<dim3(32768), blk, 0, stream>>>(qb, kb);

    // Attention (fp32 compute, bf16 in/out)
    attn_bf16<<<dim3(L_ / 64, B_ * H_), blk, 0, stream>>>(qb, kb, vb, attb);

    // Output projection (bf16 MFMA, fp32 out)
    gemm_bf16<0><<<dim3(D_ / 128, M / 128), blk, 0, stream>>>(
        attb, Wot, out, M, D_, H_ * HD_);
}

// Round 5
// 873.787 us; speedup vs baseline: 5.6676x; 2.7991x over previous
//
#include <hip/hip_runtime.h>
#include <math.h>

// Problem constants
#define B_ 2
#define L_ 2048
#define D_ 3072
#define H_ 24
#define KV_ 8
#define HD_ 128
#define GROUP_ 3
#define SCALE_ 0.08838834764831845f  // 128^-0.5
#define NEG_LOG_THETA_OVER_HALF 0.20503692627f  // ln(500000)/64

typedef __attribute__((ext_vector_type(4))) float f32x4;
typedef __attribute__((ext_vector_type(8))) short s16x8;
typedef __attribute__((ext_vector_type(8))) unsigned short u16x8;
typedef __attribute__((ext_vector_type(4))) unsigned short u16x4;

__device__ inline float b2f(unsigned short u) {
    union { unsigned int i; float f; } x;
    x.i = ((unsigned int)u) << 16;
    return x.f;
}
__device__ inline unsigned short f2b(float f) {
    union { float f; unsigned int i; } x;
    x.f = f;
    unsigned int r = x.i + 0x7FFFu + ((x.i >> 16) & 1u);  // RNE
    return (unsigned short)(r >> 16);
}

__device__ inline void gl16(const unsigned short* g, unsigned short* l) {
    // global -> LDS direct DMA, 16B/lane; LDS dest = wave-uniform base + lane*16
    __builtin_amdgcn_global_load_lds(
        (const __attribute__((address_space(1))) void*)g,
        (__attribute__((address_space(3))) void*)l, 16, 0, 0);
}

// ---------------------------------------------------------------------------
// fp32 -> bf16 row-major convert
// ---------------------------------------------------------------------------
__global__ void conv_f32_bf16(const float* __restrict__ in,
                              unsigned short* __restrict__ out, int n) {
    int i = (blockIdx.x * blockDim.x + threadIdx.x) * 4;
    if (i < n) {
        float4 v = *(const float4*)(in + i);
        u16x4 o;
        o.x = f2b(v.x); o.y = f2b(v.y); o.z = f2b(v.z); o.w = f2b(v.w);
        *(u16x4*)(out + i) = o;
    }
}

// ---------------------------------------------------------------------------
// W [K][N] fp32 -> Wt [N][K] bf16 (tiled transpose+convert). K,N % 32 == 0.
// ---------------------------------------------------------------------------
__global__ void transp_f32_bf16(const float* __restrict__ in,
                                unsigned short* __restrict__ out, int K, int N) {
    __shared__ unsigned short t[32][33];
    const int n0 = blockIdx.x * 32, k0 = blockIdx.y * 32;
    const int tx = threadIdx.x & 31, ty = threadIdx.x >> 5;  // 32 x 8
#pragma unroll
    for (int i = 0; i < 4; ++i)
        t[tx][ty + 8 * i] = f2b(in[(size_t)(k0 + ty + 8 * i) * N + n0 + tx]);
    __syncthreads();
#pragma unroll
    for (int i = 0; i < 4; ++i)
        out[(size_t)(n0 + ty + 8 * i) * K + k0 + tx] = t[ty + 8 * i][tx];
}

// ---------------------------------------------------------------------------
// bf16 MFMA GEMM (m97 structure): C[M,N] = A[M,K] @ Bt[N,K]^T
// ---------------------------------------------------------------------------
template <int OUTBF>
__global__ void gemm_bf16(const unsigned short* __restrict__ A,
                          const unsigned short* __restrict__ Bt,
                          void* __restrict__ Cv, int M, int N, int K) {
    __shared__ unsigned short sm[2][8192];

    const int tid = threadIdx.x;
    const int w = tid >> 6, lane = tid & 63;
    const int m0 = blockIdx.y * 128, n0 = blockIdx.x * 128;
    const int wm = w >> 1, wn = w & 1;
    const int l15 = lane & 15, l4 = lane >> 4;

    const int bi0 = w * 64 + lane, bi1 = (w + 4) * 64 + lane;
    const unsigned short* gA0 = A + (size_t)(m0 + (bi0 >> 2)) * K + (bi0 & 3) * 8;
    const unsigned short* gA1 = A + (size_t)(m0 + (bi1 >> 2)) * K + (bi1 & 3) * 8;
    const unsigned short* gB0 = Bt + (size_t)(n0 + (bi0 >> 2)) * K + (bi0 & 3) * 8;
    const unsigned short* gB1 = Bt + (size_t)(n0 + (bi1 >> 2)) * K + (bi1 & 3) * 8;
    const int lA0 = w * 512, lA1 = (w + 4) * 512;
    const int lB0 = 4096 + w * 512, lB1 = 4096 + (w + 4) * 512;

    f32x4 acc[4][4];
#pragma unroll
    for (int i = 0; i < 4; ++i)
#pragma unroll
        for (int j = 0; j < 4; ++j) acc[i][j] = (f32x4){0.f, 0.f, 0.f, 0.f};

    int aoff[4], boff[4];
#pragma unroll
    for (int i = 0; i < 4; ++i) {
        aoff[i] = (wm * 64 + i * 16 + l15) * 32 + l4 * 8;
        boff[i] = 4096 + (wn * 64 + i * 16 + l15) * 32 + l4 * 8;
    }

    const int nsteps = K >> 5;

    gl16(gA0, &sm[0][lA0]);
    gl16(gA1, &sm[0][lA1]);
    gl16(gB0, &sm[0][lB0]);
    gl16(gB1, &sm[0][lB1]);
    __syncthreads();

    int buf = 0;
    for (int s = 0; s < nsteps; ++s) {
        if (s + 1 < nsteps) {
            const int kt = (s + 1) << 5;
            gl16(gA0 + kt, &sm[buf ^ 1][lA0]);
            gl16(gA1 + kt, &sm[buf ^ 1][lA1]);
            gl16(gB0 + kt, &sm[buf ^ 1][lB0]);
            gl16(gB1 + kt, &sm[buf ^ 1][lB1]);
        }
        s16x8 af[4], bfr[4];
#pragma unroll
        for (int i = 0; i < 4; ++i) af[i] = *(const s16x8*)&sm[buf][aoff[i]];
#pragma unroll
        for (int i = 0; i < 4; ++i) bfr[i] = *(const s16x8*)&sm[buf][boff[i]];
#pragma unroll
        for (int mi = 0; mi < 4; ++mi)
#pragma unroll
            for (int ni = 0; ni < 4; ++ni)
                acc[mi][ni] = __builtin_amdgcn_mfma_f32_16x16x32_bf16(
                    af[mi], bfr[ni], acc[mi][ni], 0, 0, 0);
        __syncthreads();
        buf ^= 1;
    }

#pragma unroll
    for (int mi = 0; mi < 4; ++mi)
#pragma unroll
        for (int ni = 0; ni < 4; ++ni) {
            const int row0 = m0 + wm * 64 + mi * 16 + l4 * 4;
            const int col = n0 + wn * 64 + ni * 16 + l15;
#pragma unroll
            for (int r = 0; r < 4; ++r) {
                if (OUTBF)
                    ((unsigned short*)Cv)[(size_t)(row0 + r) * N + col] =
                        f2b(acc[mi][ni][r]);
                else
                    ((float*)Cv)[(size_t)(row0 + r) * N + col] = acc[mi][ni][r];
            }
        }
}

// ---------------------------------------------------------------------------
// RoPE in place on bf16 q [B,L,H,HD] and k [B,L,KV,HD].
// ---------------------------------------------------------------------------
__global__ void rope_bf16(unsigned short* __restrict__ q,
                          unsigned short* __restrict__ k) {
    const size_t nq = (size_t)B_ * L_ * H_ * 64;
    const size_t nk = (size_t)B_ * L_ * KV_ * 64;
    size_t idx = (size_t)blockIdx.x * blockDim.x + threadIdx.x;
    unsigned short* base;
    int heads;
    if (idx < nq) {
        base = q; heads = H_;
    } else if (idx < nq + nk) {
        base = k; heads = KV_; idx -= nq;
    } else {
        return;
    }
    const int i = (int)(idx & 63);
    const size_t rem = idx >> 6;
    const int l = (int)((rem / heads) % L_);

    const float inv_freq = expf(-(float)i * NEG_LOG_THETA_OVER_HALF);
    const float ang = (float)l * inv_freq;
    float s, c;
    sincosf(ang, &s, &c);

    const size_t off = rem * HD_ + i;
    const float x1 = b2f(base[off]);
    const float x2 = b2f(base[off + 64]);
    base[off] = f2b(x1 * c - x2 * s);
    base[off + 64] = f2b(x2 * c + x1 * s);
}

// ---------------------------------------------------------------------------
// MFMA causal GQA flash attention. Grid (32, 48) = (qtile, b*h). 256 thr.
// 4 waves x 16 q-rows; KV tiles of 64.
// K tile: 64 rows x 128 d = 16 chunks(16B)/row, chunk col ^= (row&7).
// V^T tile: 128 d-rows x 64 k = 8 chunks/row, chunk col ^= (row&7).
// P tile (per wave): 16 q-rows x 64 k = 8 chunks/row, chunk col ^= (row&7).
// K staged via global_load_lds with pre-swizzled global source (rule 21).
// ---------------------------------------------------------------------------
__global__ __launch_bounds__(256) void attn_mfma(
    const unsigned short* __restrict__ qg, const unsigned short* __restrict__ kg,
    const unsigned short* __restrict__ vg, unsigned short* __restrict__ att) {
    __shared__ __align__(16) unsigned short k_s[8192];     // 64k x 128d
    __shared__ __align__(16) unsigned short vt_s[8192];    // 128d x 64k
    __shared__ __align__(16) unsigned short p_s[4][1024];  // per-wave 16q x 64k

    const int tid = threadIdx.x;
    const int w = tid >> 6, lane = tid & 63;
    const int l15 = lane & 15, l4 = lane >> 4;
    const int qt = (int)gridDim.x - 1 - (int)blockIdx.x;  // big blocks first
    const int bh = blockIdx.y;
    const int b = bh / H_, h = bh % H_;
    const int g = h / GROUP_;

    // Q fragments in registers: A-frag row=l15, k-elems=(l4*8..+7) per dstep
    s16x8 qf[4];
    {
        const unsigned short* qrow =
            qg + ((size_t)(b * L_ + qt * 64 + w * 16 + l15) * H_ + h) * HD_ + l4 * 8;
#pragma unroll
        for (int i = 0; i < 4; ++i) qf[i] = *(const s16x8*)(qrow + i * 32);
    }

    f32x4 oacc[8];
#pragma unroll
    for (int i = 0; i < 8; ++i) oacc[i] = (f32x4){0.f, 0.f, 0.f, 0.f};
    float m_i[4] = {-INFINITY, -INFINITY, -INFINITY, -INFINITY};
    float l_i[4] = {0.f, 0.f, 0.f, 0.f};

    const int vk = tid >> 2;         // V stage: k row 0..63
    const int vd0 = (tid & 3) << 5;  // d base 0/32/64/96
    const int nkt = qt + 1;

    for (int kt = 0; kt < nkt; ++kt) {
        __syncthreads();  // prior tile's k_s/vt_s reads complete

        // ---- stage K tile via global_load_lds, source pre-XOR-swizzled ----
        // linear chunk c (16B): krow = c>>4 (16 chunks/row), col = c&15;
        // LDS chunk c holds K[krow][d-group (c&15)^(krow&7)]
#pragma unroll
        for (int s = 0; s < 4; ++s) {
            const int c = s * 256 + tid;
            const int krow = c >> 4;
            const int dcg = (c & 15) ^ (krow & 7);  // inverse swizzle on source
            const unsigned short* src =
                kg + ((size_t)(b * L_ + kt * 64 + krow) * KV_ + g) * HD_ + dcg * 8;
            gl16(src, &k_s[(s * 256 + (tid & 192)) * 8]);
        }

        // ---- stage V^T via registers (rotated, swizzled scalar writes) ----
        u16x8 vr[4];
        {
            const unsigned short* src =
                vg + ((size_t)(b * L_ + kt * 64 + vk) * KV_ + g) * HD_ + vd0;
#pragma unroll
            for (int i = 0; i < 4; ++i) vr[i] = *(const u16x8*)(src + 8 * i);
        }
#pragma unroll
        for (int i = 0; i < 4; ++i)
#pragma unroll
            for (int jj = 0; jj < 8; ++jj) {
                const int j = (jj + vk) & 7;  // rotation spreads banks
                const int d = vd0 + i * 8 + j;
                const int chunk = d * 8 + ((vk >> 3) ^ (d & 7));
                vt_s[chunk * 8 + (vk & 7)] = vr[i][j];
            }
        __syncthreads();

        // ---- S = Q K^T : 16 MFMAs ----
        f32x4 sacc[4];
#pragma unroll
        for (int ktile = 0; ktile < 4; ++ktile) {
            sacc[ktile] = (f32x4){0.f, 0.f, 0.f, 0.f};
#pragma unroll
            for (int ds_ = 0; ds_ < 4; ++ds_) {
                const int krow = ktile * 16 + l15;
                const int chunk = krow * 16 + ((ds_ * 4 + l4) ^ (krow & 7));
                const s16x8 kf = *(const s16x8*)&k_s[chunk * 8];
                sacc[ktile] = __builtin_amdgcn_mfma_f32_16x16x32_bf16(
                    qf[ds_], kf, sacc[ktile], 0, 0, 0);
            }
        }

        // ---- mask + scale + online softmax (16-lane-group reductions) ----
        float pv4[4][4];
#pragma unroll
        for (int r = 0; r < 4; ++r) {
            const int qglob = qt * 64 + w * 16 + l4 * 4 + r;
            float mx = -INFINITY;
#pragma unroll
            for (int ktile = 0; ktile < 4; ++ktile) {
                const int kglob = kt * 64 + ktile * 16 + l15;
                const float s =
                    (kglob <= qglob) ? sacc[ktile][r] * SCALE_ : -INFINITY;
                pv4[r][ktile] = s;
                mx = fmaxf(mx, s);
            }
#pragma unroll
            for (int off = 1; off < 16; off <<= 1)
                mx = fmaxf(mx, __shfl_xor(mx, off, 16));
            const float mn = fmaxf(m_i[r], mx);
            const float fac = __expf(m_i[r] - mn);
            m_i[r] = mn;
            float sum = 0.f;
#pragma unroll
            for (int ktile = 0; ktile < 4; ++ktile) {
                const float p = __expf(pv4[r][ktile] - mn);
                pv4[r][ktile] = p;
                sum += p;
            }
#pragma unroll
            for (int off = 1; off < 16; off <<= 1)
                sum += __shfl_xor(sum, off, 16);
            l_i[r] = l_i[r] * fac + sum;
#pragma unroll
            for (int dt = 0; dt < 8; ++dt) oacc[dt][r] *= fac;
        }

        // ---- write P (bf16) to per-wave LDS, swizzled ----
#pragma unroll
        for (int r = 0; r < 4; ++r)
#pragma unroll
            for (int ktile = 0; ktile < 4; ++ktile) {
                const int qrow = l4 * 4 + r;
                const int kcol = ktile * 16 + l15;
                const int chunk = qrow * 8 + ((kcol >> 3) ^ (qrow & 7));
                p_s[w][chunk * 8 + (kcol & 7)] = f2b(pv4[r][ktile]);
            }

        // ---- O += P V : 16 MFMAs ----
#pragma unroll
        for (int ks = 0; ks < 2; ++ks) {
            const int chunkp = l15 * 8 + ((ks * 4 + l4) ^ (l15 & 7));
            const s16x8 pf = *(const s16x8*)&p_s[w][chunkp * 8];
#pragma unroll
            for (int dt = 0; dt < 8; ++dt) {
                const int drow = dt * 16 + l15;
                const int chunk = drow * 8 + ((ks * 4 + l4) ^ (drow & 7));
                const s16x8 vf = *(const s16x8*)&vt_s[chunk * 8];
                oacc[dt] = __builtin_amdgcn_mfma_f32_16x16x32_bf16(
                    pf, vf, oacc[dt], 0, 0, 0);
            }
        }
    }

    // ---- epilogue ----
#pragma unroll
    for (int r = 0; r < 4; ++r) {
        const float inv = 1.0f / l_i[r];
        const int q = qt * 64 + w * 16 + l4 * 4 + r;
        unsigned short* dst = att + ((size_t)(b * L_ + q) * H_ + h) * HD_ + l15;
#pragma unroll
        for (int dt = 0; dt < 8; ++dt) dst[dt * 16] = f2b(oacc[dt][r] * inv);
    }
}

// ---------------------------------------------------------------------------
extern "C" void kernel_launch(void* const* d_in, const int* in_sizes, int n_in,
                              void* d_out, int out_size, void* d_ws, size_t ws_size,
                              hipStream_t stream) {
    const float* x = (const float*)d_in[0];    // [B,L,D]
    const float* Wq = (const float*)d_in[1];   // [D, H*HD]
    const float* Wk = (const float*)d_in[2];   // [D, KV*HD]
    const float* Wv = (const float*)d_in[3];   // [D, KV*HD]
    const float* Wo = (const float*)d_in[4];   // [H*HD, D]
    float* out = (float*)d_out;                // [B,L,D]

    // Workspace carve (bytes), total 117,440,512
    char* ws = (char*)d_ws;
    unsigned short* xb  = (unsigned short*)(ws);              // 25,165,824 B
    unsigned short* qb  = (unsigned short*)(ws + 25165824);   // 25,165,824 B
    unsigned short* kb  = (unsigned short*)(ws + 50331648);   //  8,388,608 B
    unsigned short* vb  = (unsigned short*)(ws + 58720256);   //  8,388,608 B
    unsigned short* Wot = (unsigned short*)(ws + 67108864);   // 18,874,368 B
    unsigned short* Wqt = (unsigned short*)(ws + 85983232);   // 18,874,368 B
    unsigned short* Wkt = (unsigned short*)(ws + 104857600);  //  6,291,456 B
    unsigned short* Wvt = (unsigned short*)(ws + 111149056);  //  6,291,456 B
    unsigned short* attb = (unsigned short*)(ws + 85983232);  // alias Wqt/Wkt

    const int M = B_ * L_;  // 4096
    dim3 blk(256);

    conv_f32_bf16<<<dim3(12288), blk, 0, stream>>>(x, xb, M * D_);
    transp_f32_bf16<<<dim3(96, 96), blk, 0, stream>>>(Wq, Wqt, D_, H_ * HD_);
    transp_f32_bf16<<<dim3(32, 96), blk, 0, stream>>>(Wk, Wkt, D_, KV_ * HD_);
    transp_f32_bf16<<<dim3(32, 96), blk, 0, stream>>>(Wv, Wvt, D_, KV_ * HD_);
    transp_f32_bf16<<<dim3(96, 96), blk, 0, stream>>>(Wo, Wot, H_ * HD_, D_);

    gemm_bf16<1><<<dim3((H_ * HD_) / 128, M / 128), blk, 0, stream>>>(
        xb, Wqt, qb, M, H_ * HD_, D_);
    gemm_bf16<1><<<dim3((KV_ * HD_) / 128, M / 128), blk, 0, stream>>>(
        xb, Wkt, kb, M, KV_ * HD_, D_);
    gemm_bf16<1><<<dim3((KV_ * HD_) / 128, M / 128), blk, 0, stream>>>(
        xb, Wvt, vb, M, KV_ * HD_, D_);

    rope_bf16<<<dim3(32768), blk, 0, stream>>>(qb, kb);

    attn_mfma<<<dim3(L_ / 64, B_ * H_), blk, 0, stream>>>(qb, kb, vb, attb);

    gemm_bf16<0><<<dim3(D_ / 128, M / 128), blk, 0, stream>>>(
        attb, Wot, out, M, D_, H_ * HD_);
}